// Round 14
// baseline (1220.169 us; speedup 1.0000x reference)
//
#include <hip/hip_runtime.h>
#include <math.h>

#define M_ROWS 2048
#define N_COLS 2048
#define DIMS 512
#define IN_STRIDE 513
#define DP_BLOCKS 32
#define DP_COLS 64
#define T_END 2112          /* M_ROWS + 64 diagonal timesteps */

constexpr float GAMMA = 0.001f;
constexpr float LOG2E = 1.44269504088896f;
constexpr float LN2   = 0.69314718055995f;

__device__ __forceinline__ float fexp2(float x) { return __builtin_amdgcn_exp2f(x); }
__device__ __forceinline__ float flog2(float x) { return __builtin_amdgcn_logf(x); }

// ---------------- argsort by timestamp (last column), stable ----------------
__global__ void argsort_kernel(const float* __restrict__ a, const float* __restrict__ b,
                               int* __restrict__ permA, int* __restrict__ permB) {
    const float* src = blockIdx.y ? b : a;
    int* perm = blockIdx.y ? permB : permA;
    __shared__ float keys[M_ROWS];
    for (int j = threadIdx.x; j < M_ROWS; j += blockDim.x)
        keys[j] = src[(size_t)j * IN_STRIDE + DIMS];
    __syncthreads();
    int i = blockIdx.x * blockDim.x + threadIdx.x;
    float ki = keys[i];
    int rank = 0;
    for (int j = 0; j < M_ROWS; ++j) {
        float kj = keys[j];
        rank += (kj < ki) || (kj == ki && j < i);
    }
    perm[rank] = i;
}

// ---------------- gather sorted rows + L2-normalize (drop time col) ----------------
__global__ __launch_bounds__(128) void norm_kernel(const float* __restrict__ a, const float* __restrict__ b,
                                                   const int* __restrict__ permA, const int* __restrict__ permB,
                                                   float* __restrict__ Ahat, float* __restrict__ Bhat) {
    const float* src = blockIdx.y ? b : a;
    const int* perm = blockIdx.y ? permB : permA;
    float* dst = blockIdx.y ? Bhat : Ahat;
    int r = blockIdx.x;
    int row = perm[r];
    const float* p = src + (size_t)row * IN_STRIDE;
    int tid = threadIdx.x;
    float v0 = p[tid], v1 = p[tid + 128], v2 = p[tid + 256], v3 = p[tid + 384];
    float ss = v0 * v0 + v1 * v1 + v2 * v2 + v3 * v3;
    #pragma unroll
    for (int off = 32; off > 0; off >>= 1) ss += __shfl_down(ss, off);
    __shared__ float red[2];
    if ((tid & 63) == 0) red[tid >> 6] = ss;
    __syncthreads();
    float inv = 1.0f / sqrtf(red[0] + red[1] + 1e-10f);
    float* q = dst + (size_t)r * DIMS;
    q[tid] = v0 * inv; q[tid + 128] = v1 * inv; q[tid + 256] = v2 * inv; q[tid + 384] = v3 * inv;
}

// ---------------- GEMM: Q[i][n] = exp(-1 - dot(Ahat[i], Bhat[n])) ----------------
__global__ __launch_bounds__(256) void gemm_kernel(const float* __restrict__ A, const float* __restrict__ B,
                                                   float* __restrict__ Q) {
    __shared__ float As[16][68];
    __shared__ float Bs[16][68];
    int tid = threadIdx.x;
    int tx = tid & 15, ty = tid >> 4;
    int row0 = blockIdx.y * 64;
    int col0 = blockIdx.x * 64;
    int lrow = tid >> 2;
    int lk = (tid & 3) * 4;
    const float* ap = A + (size_t)(row0 + lrow) * DIMS + lk;
    const float* bp = B + (size_t)(col0 + lrow) * DIMS + lk;
    float acc[4][4] = {};
    for (int k0 = 0; k0 < DIMS; k0 += 16) {
        float4 av = *(const float4*)ap; ap += 16;
        float4 bv = *(const float4*)bp; bp += 16;
        __syncthreads();
        As[lk + 0][lrow] = av.x; As[lk + 1][lrow] = av.y; As[lk + 2][lrow] = av.z; As[lk + 3][lrow] = av.w;
        Bs[lk + 0][lrow] = bv.x; Bs[lk + 1][lrow] = bv.y; Bs[lk + 2][lrow] = bv.z; Bs[lk + 3][lrow] = bv.w;
        __syncthreads();
        #pragma unroll
        for (int k = 0; k < 16; ++k) {
            float4 a4 = *(const float4*)&As[k][ty * 4];
            float4 b4 = *(const float4*)&Bs[k][tx * 4];
            float aa[4] = {a4.x, a4.y, a4.z, a4.w};
            float bb[4] = {b4.x, b4.y, b4.z, b4.w};
            #pragma unroll
            for (int u = 0; u < 4; ++u)
                #pragma unroll
                for (int v = 0; v < 4; ++v)
                    acc[u][v] += aa[u] * bb[v];
        }
    }
    #pragma unroll
    for (int u = 0; u < 4; ++u) {
        float4 o;
        o.x = __expf(-1.0f - acc[u][0]);
        o.y = __expf(-1.0f - acc[u][1]);
        o.z = __expf(-1.0f - acc[u][2]);
        o.w = __expf(-1.0f - acc[u][3]);
        *(float4*)&Q[(size_t)(row0 + ty * 4 + u) * N_COLS + col0 + tx * 4] = o;
    }
}

// ---------------- per-row softmax denom -> rs2 = log2e/(gamma*denom) ----------------
__global__ __launch_bounds__(256) void rowstat_kernel(const float* __restrict__ Q,
                                                      float* __restrict__ rowscale) {
    int i = blockIdx.x;
    const float* q = Q + (size_t)i * N_COLS;
    int tid = threadIdx.x;
    float4 x = *(const float4*)(q + tid * 4);
    float4 y = *(const float4*)(q + 1024 + tid * 4);
    float s = x.x + x.y + x.z + x.w + y.x + y.y + y.z + y.w;
    #pragma unroll
    for (int off = 32; off > 0; off >>= 1) s += __shfl_down(s, off);
    __shared__ float red[4];
    if ((tid & 63) == 0) red[tid >> 6] = s;
    __syncthreads();
    if (tid == 0) {
        float denom = 2049.0f + red[0] + red[1] + red[2] + red[3];
        rowscale[i] = (LOG2E / GAMMA) / denom;
    }
}

// ---------------- sheared weight array: D[row + (col&63)][col] = log2(We+Wo) ----------
// At diagonal timestep t, lane (col&63) of stripe col>>6 reads D[t][col]: coalesced,
// aligned — removes the per-lane misaligned column streaming of the systolic DP.
__global__ __launch_bounds__(256) void lgt_kernel(const float* __restrict__ Q,
                                                  const float* __restrict__ rowscale,
                                                  float* __restrict__ D) {
    __shared__ float tile[64][68];
    const int row0 = blockIdx.y * 64;
    const int col0 = blockIdx.x * 64;
    const int t = threadIdx.x;
    const int c4 = (t & 15) * 4;
    const int r  = t >> 4;           // 0..15
    #pragma unroll
    for (int rr = 0; rr < 64; rr += 16) {
        int row = row0 + rr + r;
        float rs = rowscale[row];
        float4 v = *(const float4*)(Q + (size_t)row * N_COLS + col0 + c4);
        float e = fexp2(-rs);
        float4 o;
        o.x = flog2(e + fexp2(-rs * v.x));
        o.y = flog2(e + fexp2(-rs * v.y));
        o.z = flog2(e + fexp2(-rs * v.z));
        o.w = flog2(e + fexp2(-rs * v.w));
        *(float4*)&tile[rr + r][c4] = o;
    }
    __syncthreads();
    const int wave = t >> 6, lane = t & 63;
    for (int dt = wave; dt < 127; dt += 4) {
        int rl = dt - lane;                       // local row for this lane
        if (rl >= 0 && rl < 64)
            D[(size_t)(row0 + dt) * N_COLS + col0 + lane] = tile[rl][lane];
    }
}

// ---------------- sheared rowscale: RsD[t][lane] = rowscale[t - lane] (0 outside) ----
__global__ __launch_bounds__(256) void rsd_kernel(const float* __restrict__ rowscale,
                                                  float* __restrict__ RsD) {
    int idx = blockIdx.x * 256 + threadIdx.x;    // < T_END*64
    int trow = idx >> 6, lane = idx & 63;
    int i = trow - lane;
    RsD[idx] = ((unsigned)i < (unsigned)M_ROWS) ? rowscale[i] : 0.f;
}

// ---------------- (m,s) pair arithmetic: value = m + log2(s) ----------------
struct Pair { float m, s; };
constexpr float ID_M = -1e30f;

__device__ __forceinline__ Pair pcomb(Pair a, Pair b) {
    float e = fexp2(-fabsf(a.m - b.m));
    bool c = a.m >= b.m;
    Pair r;
    r.m = c ? a.m : b.m;
    r.s = c ? fmaf(b.s, e, a.s) : fmaf(a.s, e, b.s);
    return r;
}
__device__ __forceinline__ void renorm(float& m, float& s) {
    int bits = __float_as_int(s);
    int ex = ((bits >> 23) & 255) - 127;
    m += (float)ex;
    s = __int_as_float(bits - (ex << 23));
}
template<int CTRL, int ROWM>
__device__ __forceinline__ float fdpp(float oldv, float src) {
    return __int_as_float(__builtin_amdgcn_update_dpp(
        __float_as_int(oldv), __float_as_int(src), CTRL, ROWM, 0xF, false));
}
// lane (n-1) value, crossing 16-lane DPP row boundaries; lane 0 gets idv
__device__ __forceinline__ float lane_prev(float x, int lane, float idv) {
    float am = fdpp<0x111,0xF>(idv, x);
    float bm = fdpp<0x142,0xA>(idv, x);
    float cm = fdpp<0x143,0x4>(idv, x);
    bool s15 = (lane == 16) || (lane == 48);
    bool s31 = (lane == 32);
    return s15 ? bm : (s31 ? cm : am);
}

// ---------------- systolic DP: lane g processes row i at t = i + (g&63) ------------
// Per timestep: Sl = neighbor's previous-step S (DPP; lane0 <- inter-block carry);
//   S  = Sl (+) {mP + D[t][col], sP}      (inclusive prefix through this column)
//   P' = Sl (+) {mP - rs, sP}             (gated by row validity)
// Lane 63 publishes S (the stripe total for its row) — banded poll as before.
// Block 31 lane 63 folds h (column 4096): h' = S (+) {mH - rs, sH}; loss = val(h).
#define ROW_STEP(U, DV, RV)                                                     \
    {                                                                           \
        const int t = tb + (U);                                                 \
        float cm = ID_M, cs = 0.f;                                              \
        if (s > 0) {                                                            \
            cm = __int_as_float(__builtin_amdgcn_readlane(pkLo, (U)));          \
            cs = __int_as_float(__builtin_amdgcn_readlane(pkHi, (U)));          \
        }                                                                       \
        float slm = lane_prev(Snm, lane, cm);                                   \
        float sls = lane_prev(Sns, lane, cs);                                   \
        Pair sl{slm, sls};                                                      \
        Pair sn = pcomb(sl, Pair{mP + (DV), sP});                               \
        Pair pn = pcomb(sl, Pair{mP - (RV), sP});                               \
        bool valid = (unsigned)(t - lane) < (unsigned)M_ROWS;                   \
        mP = valid ? pn.m : mP;                                                 \
        sP = valid ? pn.s : sP;                                                 \
        renorm(mP, sP);                                                         \
        if (s == DP_BLOCKS - 1) {                                               \
            Pair hh = pcomb(sn, Pair{mH - (RV), sH});                           \
            bool hv = valid && (lane == 63);                                    \
            mH = hv ? hh.m : mH;                                                \
            sH = hv ? hh.s : sH;                                                \
            renorm(mH, sH);                                                     \
        } else if ((unsigned)(t - 63) < (unsigned)M_ROWS) {                     \
            if (lane == 63) {                                                   \
                unsigned long long po =                                         \
                    ((unsigned long long)__float_as_uint(sn.s) << 32)           \
                    | (unsigned long long)__float_as_uint(sn.m);                \
                __hip_atomic_store(pub + (t - 63), po, __ATOMIC_RELAXED,        \
                                   __HIP_MEMORY_SCOPE_AGENT);                   \
            }                                                                   \
        }                                                                       \
        Snm = sn.m; Sns = sn.s;                                                 \
    }

#define REP16(F) F(0) F(1) F(2) F(3) F(4) F(5) F(6) F(7) F(8) F(9) F(10) F(11) F(12) F(13) F(14) F(15)
#define DECLV(U) float d##U = 0.f, e##U = 0.f, r##U = 0.f, q##U = 0.f;
#define LOAD_FIRST(U) d##U = dcol[(size_t)(U) * N_COLS]; r##U = rcol[(U) * DP_COLS];
#define LOAD_NEXT(U)  e##U = dcol[(size_t)(tb + 16 + (U)) * N_COLS]; q##U = rcol[(tb + 16 + (U)) * DP_COLS];
#define MOVB(U) d##U = e##U; r##U = q##U;
#define STEP(U) ROW_STEP(U, d##U, r##U)

__global__ __launch_bounds__(64) void dp_kernel(const float* __restrict__ D,
                                                const float* __restrict__ RsD,
                                                unsigned long long* __restrict__ carry,
                                                float* __restrict__ out) {
    const int s = ((blockIdx.x & 7) << 2) | (blockIdx.x >> 3);  // XCD-aware stripe id
    const int lane = threadIdx.x;
    const float* dcol = D + s * DP_COLS + lane;
    const float* rcol = RsD + lane;
    unsigned long long* pub = carry + (size_t)s * M_ROWS;
    const unsigned long long* sub = carry + (size_t)(s - 1) * M_ROWS;

    float mP = 0.f, sP = 1.f;      // P state (virtual row -1 = log2(1))
    float mH = 0.f, sH = 1.f;      // stripe 31 lane 63 only
    float Snm = ID_M, Sns = 0.f;   // neighbor-chain value from previous timestep

    REP16(DECLV)
    REP16(LOAD_FIRST)

    for (int tb = 0; tb < T_END; tb += 16) {
        // banded carry poll: lane u<16 spins on row tb+u of the left stripe
        unsigned long long pk = 1ull;
        if (s > 0 && lane < 16 && tb + lane < M_ROWS) {
            const unsigned long long* p = sub + tb + lane;
            do {
                pk = __hip_atomic_load(p, __ATOMIC_RELAXED, __HIP_MEMORY_SCOPE_AGENT);
            } while (pk == 0ull);
        }
        int pkLo = (int)(unsigned)(pk & 0xFFFFFFFFull);
        int pkHi = (int)(unsigned)(pk >> 32);

        // prefetch next band (named registers, static indices; completes during rows)
        if (tb + 16 < T_END) { REP16(LOAD_NEXT) }

        REP16(STEP)
        REP16(MOVB)
    }
    if (s == DP_BLOCKS - 1 && lane == 63)
        out[0] = -GAMMA * LN2 * (mH + flog2(sH));
}

extern "C" void kernel_launch(void* const* d_in, const int* in_sizes, int n_in,
                              void* d_out, int out_size, void* d_ws, size_t ws_size,
                              hipStream_t stream) {
    (void)in_sizes; (void)n_in; (void)out_size; (void)ws_size;
    const float* a = (const float*)d_in[0];
    const float* b = (const float*)d_in[1];
    float* out = (float*)d_out;
    char* ws = (char*)d_ws;
    float* Q        = (float*)(ws);                                    // 16 MB
    float* D        = (float*)(ws + (size_t)16 * 1024 * 1024);         // 16.5 MB (T_END x 2048)
    float* Ahat     = (float*)(ws + (size_t)33 * 1024 * 1024);         // 4 MB
    float* Bhat     = (float*)(ws + (size_t)37 * 1024 * 1024);         // 4 MB
    float* rowscale = (float*)(ws + (size_t)41 * 1024 * 1024);         // 8 KB
    int* permA      = (int*)(ws + (size_t)41 * 1024 * 1024 + 8192);    // 8 KB
    int* permB      = (int*)(ws + (size_t)41 * 1024 * 1024 + 16384);   // 8 KB
    float* RsD      = (float*)(ws + (size_t)42 * 1024 * 1024);         // 528 KB (T_END x 64)
    unsigned long long* carry = (unsigned long long*)(ws + (size_t)43 * 1024 * 1024); // 512 KB

    hipMemsetAsync(carry, 0, (size_t)DP_BLOCKS * M_ROWS * sizeof(unsigned long long), stream);
    argsort_kernel<<<dim3(8, 2), 256, 0, stream>>>(a, b, permA, permB);
    norm_kernel<<<dim3(2048, 2), 128, 0, stream>>>(a, b, permA, permB, Ahat, Bhat);
    gemm_kernel<<<dim3(32, 32), 256, 0, stream>>>(Ahat, Bhat, Q);
    rowstat_kernel<<<2048, 256, 0, stream>>>(Q, rowscale);
    rsd_kernel<<<(T_END * 64) / 256, 256, 0, stream>>>(rowscale, RsD);
    lgt_kernel<<<dim3(32, 32), 256, 0, stream>>>(Q, rowscale, D);
    dp_kernel<<<DP_BLOCKS, DP_COLS, 0, stream>>>(D, RsD, carry, out);
}

// Round 15
// 886.550 us; speedup vs baseline: 1.3763x; 1.3763x over previous
//
#include <hip/hip_runtime.h>
#include <math.h>

#define M_ROWS 2048
#define N_COLS 2048
#define DIMS 512
#define IN_STRIDE 513
#define DP_BLOCKS 32
#define DP_COLS 64
#define BAND 16

constexpr float GAMMA = 0.001f;
constexpr float LOG2E = 1.44269504088896f;
constexpr float LN2   = 0.69314718055995f;

__device__ __forceinline__ float fexp2(float x) { return __builtin_amdgcn_exp2f(x); }
__device__ __forceinline__ float flog2(float x) { return __builtin_amdgcn_logf(x); }

// ---------------- argsort by timestamp (last column), stable ----------------
__global__ void argsort_kernel(const float* __restrict__ a, const float* __restrict__ b,
                               int* __restrict__ permA, int* __restrict__ permB) {
    const float* src = blockIdx.y ? b : a;
    int* perm = blockIdx.y ? permB : permA;
    __shared__ float keys[M_ROWS];
    for (int j = threadIdx.x; j < M_ROWS; j += blockDim.x)
        keys[j] = src[(size_t)j * IN_STRIDE + DIMS];
    __syncthreads();
    int i = blockIdx.x * blockDim.x + threadIdx.x;
    float ki = keys[i];
    int rank = 0;
    for (int j = 0; j < M_ROWS; ++j) {
        float kj = keys[j];
        rank += (kj < ki) || (kj == ki && j < i);
    }
    perm[rank] = i;
}

// ---------------- gather sorted rows + L2-normalize (drop time col) ----------------
__global__ __launch_bounds__(128) void norm_kernel(const float* __restrict__ a, const float* __restrict__ b,
                                                   const int* __restrict__ permA, const int* __restrict__ permB,
                                                   float* __restrict__ Ahat, float* __restrict__ Bhat) {
    const float* src = blockIdx.y ? b : a;
    const int* perm = blockIdx.y ? permB : permA;
    float* dst = blockIdx.y ? Bhat : Ahat;
    int r = blockIdx.x;
    int row = perm[r];
    const float* p = src + (size_t)row * IN_STRIDE;
    int tid = threadIdx.x;
    float v0 = p[tid], v1 = p[tid + 128], v2 = p[tid + 256], v3 = p[tid + 384];
    float ss = v0 * v0 + v1 * v1 + v2 * v2 + v3 * v3;
    #pragma unroll
    for (int off = 32; off > 0; off >>= 1) ss += __shfl_down(ss, off);
    __shared__ float red[2];
    if ((tid & 63) == 0) red[tid >> 6] = ss;
    __syncthreads();
    float inv = 1.0f / sqrtf(red[0] + red[1] + 1e-10f);
    float* q = dst + (size_t)r * DIMS;
    q[tid] = v0 * inv; q[tid + 128] = v1 * inv; q[tid + 256] = v2 * inv; q[tid + 384] = v3 * inv;
}

// ---------------- GEMM: Q[i][n] = exp(-1 - dot(Ahat[i], Bhat[n])) ----------------
__global__ __launch_bounds__(256) void gemm_kernel(const float* __restrict__ A, const float* __restrict__ B,
                                                   float* __restrict__ Q) {
    __shared__ float As[16][68];
    __shared__ float Bs[16][68];
    int tid = threadIdx.x;
    int tx = tid & 15, ty = tid >> 4;
    int row0 = blockIdx.y * 64;
    int col0 = blockIdx.x * 64;
    int lrow = tid >> 2;
    int lk = (tid & 3) * 4;
    const float* ap = A + (size_t)(row0 + lrow) * DIMS + lk;
    const float* bp = B + (size_t)(col0 + lrow) * DIMS + lk;
    float acc[4][4] = {};
    for (int k0 = 0; k0 < DIMS; k0 += 16) {
        float4 av = *(const float4*)ap; ap += 16;
        float4 bv = *(const float4*)bp; bp += 16;
        __syncthreads();
        As[lk + 0][lrow] = av.x; As[lk + 1][lrow] = av.y; As[lk + 2][lrow] = av.z; As[lk + 3][lrow] = av.w;
        Bs[lk + 0][lrow] = bv.x; Bs[lk + 1][lrow] = bv.y; Bs[lk + 2][lrow] = bv.z; Bs[lk + 3][lrow] = bv.w;
        __syncthreads();
        #pragma unroll
        for (int k = 0; k < 16; ++k) {
            float4 a4 = *(const float4*)&As[k][ty * 4];
            float4 b4 = *(const float4*)&Bs[k][tx * 4];
            float aa[4] = {a4.x, a4.y, a4.z, a4.w};
            float bb[4] = {b4.x, b4.y, b4.z, b4.w};
            #pragma unroll
            for (int u = 0; u < 4; ++u)
                #pragma unroll
                for (int v = 0; v < 4; ++v)
                    acc[u][v] += aa[u] * bb[v];
        }
    }
    #pragma unroll
    for (int u = 0; u < 4; ++u) {
        float4 o;
        o.x = __expf(-1.0f - acc[u][0]);
        o.y = __expf(-1.0f - acc[u][1]);
        o.z = __expf(-1.0f - acc[u][2]);
        o.w = __expf(-1.0f - acc[u][3]);
        *(float4*)&Q[(size_t)(row0 + ty * 4 + u) * N_COLS + col0 + tx * 4] = o;
    }
}

// ---------------- per-row softmax denom -> rs2 = log2e/(gamma*denom) ----------------
__global__ __launch_bounds__(256) void rowstat_kernel(const float* __restrict__ Q,
                                                      float* __restrict__ rowscale) {
    int i = blockIdx.x;
    const float* q = Q + (size_t)i * N_COLS;
    int tid = threadIdx.x;
    float4 x = *(const float4*)(q + tid * 4);
    float4 y = *(const float4*)(q + 1024 + tid * 4);
    float s = x.x + x.y + x.z + x.w + y.x + y.y + y.z + y.w;
    #pragma unroll
    for (int off = 32; off > 0; off >>= 1) s += __shfl_down(s, off);
    __shared__ float red[4];
    if ((tid & 63) == 0) red[tid >> 6] = s;
    __syncthreads();
    if (tid == 0) {
        float denom = 2049.0f + red[0] + red[1] + red[2] + red[3];
        rowscale[i] = (LOG2E / GAMMA) / denom;
    }
}

// ---------------- LG2T[col][row] = log2(We_row + Wo_row[col]), tiled transpose ----------
__global__ __launch_bounds__(256) void lgt_kernel(const float* __restrict__ Q,
                                                  const float* __restrict__ rowscale,
                                                  float* __restrict__ LG2T) {
    __shared__ float tile[64][65];
    const int row0 = blockIdx.y * 64;
    const int col0 = blockIdx.x * 64;
    const int t = threadIdx.x;
    const int c4 = (t & 15) * 4;
    const int r  = t >> 4;           // 0..15
    #pragma unroll
    for (int rr = 0; rr < 64; rr += 16) {
        int row = row0 + rr + r;
        float rs = rowscale[row];
        float4 v = *(const float4*)(Q + (size_t)row * N_COLS + col0 + c4);
        float e = fexp2(-rs);
        tile[c4 + 0][rr + r] = flog2(e + fexp2(-rs * v.x));
        tile[c4 + 1][rr + r] = flog2(e + fexp2(-rs * v.y));
        tile[c4 + 2][rr + r] = flog2(e + fexp2(-rs * v.z));
        tile[c4 + 3][rr + r] = flog2(e + fexp2(-rs * v.w));
    }
    __syncthreads();
    #pragma unroll
    for (int cc = 0; cc < 64; cc += 16) {
        int col = cc + r;
        float4 o;
        o.x = tile[col][c4 + 0];
        o.y = tile[col][c4 + 1];
        o.z = tile[col][c4 + 2];
        o.w = tile[col][c4 + 3];
        *(float4*)(LG2T + (size_t)(col0 + col) * M_ROWS + row0 + c4) = o;
    }
}

// ---------------- (m,s) pair arithmetic: value = m + log2(s) ----------------
struct Pair { float m, s; };
constexpr float ID_M = -1e30f;

__device__ __forceinline__ Pair pcomb(Pair a, Pair b) {
    float e = fexp2(-fabsf(a.m - b.m));
    bool c = a.m >= b.m;
    Pair r;
    r.m = c ? a.m : b.m;
    r.s = c ? fmaf(b.s, e, a.s) : fmaf(a.s, e, b.s);
    return r;
}
__device__ __forceinline__ void renorm(float& m, float& s) {
    int bits = __float_as_int(s);
    int ex = ((bits >> 23) & 255) - 127;
    m += (float)ex;
    s = __int_as_float(bits - (ex << 23));
}
template<int CTRL, int ROWM>
__device__ __forceinline__ float fdpp(float oldv, float src) {
    return __int_as_float(__builtin_amdgcn_update_dpp(
        __float_as_int(oldv), __float_as_int(src), CTRL, ROWM, 0xF, false));
}
// wave64 inclusive AFFINE scan: S[n] = S[n-1]*a[n] + z[n]; mul+fma only.
__device__ __forceinline__ void affine_scan(float& A, float& S) {
    { float Ap = fdpp<0x111,0xF>(1.0f, A), Sp = fdpp<0x111,0xF>(0.0f, S); S = fmaf(Sp, A, S); A = A * Ap; }
    { float Ap = fdpp<0x112,0xF>(1.0f, A), Sp = fdpp<0x112,0xF>(0.0f, S); S = fmaf(Sp, A, S); A = A * Ap; }
    { float Ap = fdpp<0x114,0xF>(1.0f, A), Sp = fdpp<0x114,0xF>(0.0f, S); S = fmaf(Sp, A, S); A = A * Ap; }
    { float Ap = fdpp<0x118,0xF>(1.0f, A), Sp = fdpp<0x118,0xF>(0.0f, S); S = fmaf(Sp, A, S); A = A * Ap; }
    { float Ap = fdpp<0x142,0xA>(1.0f, A), Sp = fdpp<0x142,0xA>(0.0f, S); S = fmaf(Sp, A, S); A = A * Ap; }
    { float Ap = fdpp<0x143,0xC>(1.0f, A), Sp = fdpp<0x143,0xC>(0.0f, S); S = fmaf(Sp, A, S); A = A * Ap; }
}
// lane (n-1) value, crossing 16-lane DPP row boundaries; lane 0 gets idv
__device__ __forceinline__ float lane_prev(float x, int lane, float idv) {
    float am = fdpp<0x111,0xF>(idv, x);
    float bm = fdpp<0x142,0xA>(idv, x);
    float cm = fdpp<0x143,0x4>(idv, x);
    bool s15 = (lane == 16) || (lane == 48);
    bool s31 = (lane == 32);
    return s15 ? bm : (s31 ? cm : am);
}

// ---------------- MAXLESS row body ----------------
// P[n] is non-decreasing in n (P_new = LSE(S[n-1], lwe+P_old[n]); both args monotone
// by induction), so G[n] = mP + LG2 is monotone up to +-1.6 and serves as the LSE
// shift directly: a = 2^(G[n-1]-G[n]) (<= ~3), z = sP (<2). T = affine_scan sum
// <= ~400 — no overflow, no max-scan needed. Inclusive prefix pair = {G, T}.
// Chain depth ~26 ops vs round 13's ~39 (empirical law: T_row ~ 25cy x depth).
#define DP_ROW(U, LGV, RSV)                                                      \
    {                                                                            \
        const int row = base + (U);                                              \
        float lwe = -(RSV);                                                      \
        float G = mP + (LGV);                                                    \
        float Gp = lane_prev(G, lane, ID_M);       /* lane0 -> -1e30 */          \
        float A = fexp2(Gp - G);                   /* lane0 -> 0 */              \
        float S = sP;                                                            \
        affine_scan(A, S);                                                       \
        float Tp = lane_prev(S, lane, 0.0f);                                     \
        Pair cin{ID_M, 0.f};                                                     \
        if (s > 0) {                                                             \
            cin.m = __int_as_float(__builtin_amdgcn_readlane(pkLo, (U)));        \
            cin.s = __int_as_float(__builtin_amdgcn_readlane(pkHi, (U)));        \
        }                                                                        \
        Pair v{G, S};                                                            \
        if (s < DP_BLOCKS - 1) {                                                 \
            if (lane == 63) {                                                    \
                Pair tot = pcomb(cin, v);                                        \
                unsigned long long po =                                          \
                    ((unsigned long long)__float_as_uint(tot.s) << 32)           \
                    | (unsigned long long)__float_as_uint(tot.m);                \
                __hip_atomic_store(pub + row, po, __ATOMIC_RELAXED,              \
                                   __HIP_MEMORY_SCOPE_AGENT);                    \
            }                                                                    \
        } else {                                                                 \
            Pair tot = pcomb(cin, v);                                            \
            Pair hh = pcomb(tot, Pair{mH + lwe, sH});                            \
            mH = hh.m; sH = hh.s;                                                \
            renorm(mH, sH);                                                      \
        }                                                                        \
        float dm = mP + lwe;                                                     \
        float m3 = fmaxf(fmaxf(cin.m, Gp), dm);                                  \
        float s3 = cin.s * fexp2(cin.m - m3)                                     \
                 + Tp   * fexp2(Gp    - m3)                                      \
                 + sP   * fexp2(dm    - m3);                                     \
        mP = m3; sP = s3;                                                        \
        renorm(mP, sP);                                                          \
    }

__global__ __launch_bounds__(64) void dp_kernel(const float* __restrict__ LG2T,
                                                const float* __restrict__ Rs,
                                                unsigned long long* __restrict__ carry,
                                                float* __restrict__ out) {
    const int s = ((blockIdx.x & 7) << 2) | (blockIdx.x >> 3);  // XCD-aware stripe id
    const int lane = threadIdx.x;
    const float* lcol = LG2T + (size_t)(s * DP_COLS + lane) * M_ROWS;
    unsigned long long* pub = carry + (size_t)s * M_ROWS;
    const unsigned long long* sub = carry + (size_t)(s - 1) * M_ROWS;

    float mP = 0.f, sP = 1.f;      // virtual row -1: P = log2(1)
    float mH = 0.f, sH = 1.f;      // stripe 31, lane 63 only

    float4 lq0 = *(const float4*)(lcol + 0);
    float4 lq1 = *(const float4*)(lcol + 4);
    float4 lq2 = *(const float4*)(lcol + 8);
    float4 lq3 = *(const float4*)(lcol + 12);
    float4 rv0 = *(const float4*)(Rs + 0);
    float4 rv1 = *(const float4*)(Rs + 4);
    float4 rv2 = *(const float4*)(Rs + 8);
    float4 rv3 = *(const float4*)(Rs + 12);

    // speculative carry prefetch for band 0
    unsigned long long pk = 1ull;
    if (s > 0 && lane < BAND)
        pk = __hip_atomic_load(sub + lane, __ATOMIC_RELAXED, __HIP_MEMORY_SCOPE_AGENT);

    for (int base = 0; base < M_ROWS; base += BAND) {
        // prefetch next band's weights (independent; completes during the 16 rows)
        float4 nl0{}, nl1{}, nl2{}, nl3{}, nv0{}, nv1{}, nv2{}, nv3{};
        if (base + BAND < M_ROWS) {
            nl0 = *(const float4*)(lcol + base + BAND);
            nl1 = *(const float4*)(lcol + base + BAND + 4);
            nl2 = *(const float4*)(lcol + base + BAND + 8);
            nl3 = *(const float4*)(lcol + base + BAND + 12);
            nv0 = *(const float4*)(Rs + base + BAND);
            nv1 = *(const float4*)(Rs + base + BAND + 4);
            nv2 = *(const float4*)(Rs + base + BAND + 8);
            nv3 = *(const float4*)(Rs + base + BAND + 12);
        }
        // finish this band's carry poll (speculative load usually already succeeded)
        if (s > 0 && lane < BAND) {
            const unsigned long long* p = sub + base + lane;
            while (pk == 0ull)
                pk = __hip_atomic_load(p, __ATOMIC_RELAXED, __HIP_MEMORY_SCOPE_AGENT);
        }
        int pkLo = (int)(unsigned)(pk & 0xFFFFFFFFull);
        int pkHi = (int)(unsigned)(pk >> 32);
        // speculative carry load for the NEXT band (in flight during the 16 rows)
        unsigned long long nk = 1ull;
        if (s > 0 && lane < BAND && base + BAND < M_ROWS)
            nk = __hip_atomic_load(sub + base + BAND + lane,
                                   __ATOMIC_RELAXED, __HIP_MEMORY_SCOPE_AGENT);

        DP_ROW(0,  lq0.x, rv0.x)
        DP_ROW(1,  lq0.y, rv0.y)
        DP_ROW(2,  lq0.z, rv0.z)
        DP_ROW(3,  lq0.w, rv0.w)
        DP_ROW(4,  lq1.x, rv1.x)
        DP_ROW(5,  lq1.y, rv1.y)
        DP_ROW(6,  lq1.z, rv1.z)
        DP_ROW(7,  lq1.w, rv1.w)
        DP_ROW(8,  lq2.x, rv2.x)
        DP_ROW(9,  lq2.y, rv2.y)
        DP_ROW(10, lq2.z, rv2.z)
        DP_ROW(11, lq2.w, rv2.w)
        DP_ROW(12, lq3.x, rv3.x)
        DP_ROW(13, lq3.y, rv3.y)
        DP_ROW(14, lq3.z, rv3.z)
        DP_ROW(15, lq3.w, rv3.w)

        lq0 = nl0; lq1 = nl1; lq2 = nl2; lq3 = nl3;
        rv0 = nv0; rv1 = nv1; rv2 = nv2; rv3 = nv3;
        pk = nk;
    }
    if (s == DP_BLOCKS - 1 && lane == 63)
        out[0] = -GAMMA * LN2 * (mH + flog2(sH));
}

extern "C" void kernel_launch(void* const* d_in, const int* in_sizes, int n_in,
                              void* d_out, int out_size, void* d_ws, size_t ws_size,
                              hipStream_t stream) {
    (void)in_sizes; (void)n_in; (void)out_size; (void)ws_size;
    const float* a = (const float*)d_in[0];
    const float* b = (const float*)d_in[1];
    float* out = (float*)d_out;
    char* ws = (char*)d_ws;
    float* Q        = (float*)(ws);                                    // 16 MB
    float* LG2T     = (float*)(ws + (size_t)16 * 1024 * 1024);         // 16 MB
    float* Ahat     = (float*)(ws + (size_t)32 * 1024 * 1024);         // 4 MB
    float* Bhat     = (float*)(ws + (size_t)36 * 1024 * 1024);         // 4 MB
    float* rowscale = (float*)(ws + (size_t)40 * 1024 * 1024);         // 8 KB
    int* permA      = (int*)(ws + (size_t)40 * 1024 * 1024 + 8192);    // 8 KB
    int* permB      = (int*)(ws + (size_t)40 * 1024 * 1024 + 16384);   // 8 KB
    unsigned long long* carry = (unsigned long long*)(ws + (size_t)41 * 1024 * 1024); // 512 KB

    hipMemsetAsync(carry, 0, (size_t)DP_BLOCKS * M_ROWS * sizeof(unsigned long long), stream);
    argsort_kernel<<<dim3(8, 2), 256, 0, stream>>>(a, b, permA, permB);
    norm_kernel<<<dim3(2048, 2), 128, 0, stream>>>(a, b, permA, permB, Ahat, Bhat);
    gemm_kernel<<<dim3(32, 32), 256, 0, stream>>>(Ahat, Bhat, Q);
    rowstat_kernel<<<2048, 256, 0, stream>>>(Q, rowscale);
    lgt_kernel<<<dim3(32, 32), 256, 0, stream>>>(Q, rowscale, LG2T);
    dp_kernel<<<DP_BLOCKS, DP_COLS, 0, stream>>>(LG2T, rowscale, carry, out);
}